// Round 1
// 422.929 us; speedup vs baseline: 1.0193x; 1.0193x over previous
//
#include <hip/hip_runtime.h>

// Reverse (suffix) cumsum along dim=1 of (2048, 32768) fp32.
// One block per row, 1024 threads (16 waves), 8 float4 tiles per thread.
// vs previous version (512 thr / 16 tiles): halved per-thread register tile
// (~32 fewer VGPRs for v[], 8 fewer for excl[]) to raise occupancy and let
// resident blocks interleave their read/write bursts; non-temporal loads and
// stores keep the zero-reuse 512 MiB stream from thrashing L2/L3.

#define T 1024              // threads per block (16 waves)
#define WAVES 16
#define TILES 8             // (32768/4) / 1024

typedef float f32x4 __attribute__((ext_vector_type(4)));

__global__ __launch_bounds__(T, 4) void rcumsum_rows(const float* __restrict__ x,
                                                     float* __restrict__ out,
                                                     int N) {
    __shared__ float wtot[TILES][WAVES];   // per-(tile,wave) totals

    const int row = blockIdx.x;
    const long long rowbase = (long long)row * (long long)N;
    const f32x4* __restrict__ xin  = (const f32x4*)(x + rowbase);
    f32x4* __restrict__       xout = (f32x4*)(out + rowbase);

    const int tid  = threadIdx.x;
    const int lane = tid & 63;
    const int wave = tid >> 6;

    // Phase 1: issue ALL loads up front — 8 outstanding per thread,
    // non-temporal (read-once stream).
    f32x4 v[TILES];
    #pragma unroll
    for (int t = 0; t < TILES; ++t)
        v[t] = __builtin_nontemporal_load(&xin[t * T + tid]);

    // Phase 2: per-tile wave-level suffix scans (independent across tiles).
    // excl[t] = exclusive suffix (sum of group-sums of lanes > lane).
    float excl[TILES];
    #pragma unroll
    for (int t = 0; t < TILES; ++t) {
        float g = v[t].x + v[t].y + v[t].z + v[t].w;   // this thread's group sum
        float acc = g;                                  // inclusive suffix scan
        #pragma unroll
        for (int d = 1; d < 64; d <<= 1) {
            float tmp = __shfl_down(acc, d);
            if (lane + d < 64) acc += tmp;
        }
        excl[t] = acc - g;
        if (lane == 0) wtot[t][wave] = acc;             // wave total
    }
    __syncthreads();   // the ONLY barrier

    // Phase 3: redundant carry computation from broadcast LDS reads + stores.
    float carry = 0.0f;
    #pragma unroll
    for (int t = TILES - 1; t >= 0; --t) {
        float tt = 0.0f, wo = 0.0f;
        #pragma unroll
        for (int w = 0; w < WAVES; ++w) {
            float val = wtot[t][w];      // wave-uniform addr: broadcast, no conflict
            tt += val;
            if (w > wave) wo += val;
        }
        float add = excl[t] + wo + carry;

        float l3 = v[t].w;
        float l2 = v[t].z + l3;
        float l1 = v[t].y + l2;
        float l0 = v[t].x + l1;

        f32x4 o;
        o.x = l0 + add;
        o.y = l1 + add;
        o.z = l2 + add;
        o.w = l3 + add;
        __builtin_nontemporal_store(o, &xout[t * T + tid]);

        carry += tt;
    }
}

extern "C" void kernel_launch(void* const* d_in, const int* in_sizes, int n_in,
                              void* d_out, int out_size, void* d_ws, size_t ws_size,
                              hipStream_t stream) {
    const float* x = (const float*)d_in[0];
    float* out = (float*)d_out;

    const int N = 32768;
    const int B = out_size / N;   // 2048 rows

    rcumsum_rows<<<B, T, 0, stream>>>(x, out, N);
}